// Round 7
// baseline (146.207 us; speedup 1.0000x reference)
//
#include <hip/hip_runtime.h>

#define MAXCB    2880               // bytes per staged matrix chunk (max of 2688 tab / 2880 f0)
#define WAVE_LDS (2 * MAXCB)        // pred chunk + gt chunk per wave (5760 B)

// Named members only — no arrays anywhere, so SROA keeps these in VGPRs.
struct C6 { float4 p0, p1, p2, g0, g1, g2; };

// Chunk image: CB bytes per matrix, segments [0,1024), [1024,2048), [2048,CB).
// Third segment offset is CLAMPED (not branch-masked): lanes past the tail
// re-read / re-write the last 16B slot with identical data — branchless & uniform.
template<int CB>
__device__ __forceinline__ C6 load_chunk(const char* __restrict__ p,
                                         const char* __restrict__ g, int lane) {
    const int off = lane * 16;
    const int o2  = (off + 2048 <= CB - 16) ? (off + 2048) : (CB - 16);
    C6 c;
    c.p0 = *(const float4*)(p + off);
    c.p1 = *(const float4*)(p + 1024 + off);
    c.p2 = *(const float4*)(p + o2);
    c.g0 = *(const float4*)(g + off);
    c.g1 = *(const float4*)(g + 1024 + off);
    c.g2 = *(const float4*)(g + o2);
    return c;
}

template<int CB>
__device__ __forceinline__ void store_chunk(char* lbuf, int lane, const C6& c) {
    const int off = lane * 16;
    const int o2  = (off + 2048 <= CB - 16) ? (off + 2048) : (CB - 16);
    *(float4*)(lbuf + off)                = c.p0;
    *(float4*)(lbuf + 1024 + off)         = c.p1;
    *(float4*)(lbuf + o2)                 = c.p2;
    *(float4*)(lbuf + MAXCB + off)        = c.g0;
    *(float4*)(lbuf + MAXCB + 1024 + off) = c.g1;
    *(float4*)(lbuf + MAXCB + o2)         = c.g2;
}

// Lanes [0,H): argmax of pred rows; lanes [32,32+H): argmax of gt rows; shfl-combine.
template<int NC, int H, bool TAB>
__device__ __forceinline__ void compute_chunk(const char* lbuf, int lane, int chunk,
                                              int gtlen, unsigned& tp, unsigned& fp,
                                              unsigned& fn)
{
    const int r = lane & 31;
    const float* row = (const float*)(lbuf + ((lane >= 32) ? MAXCB : 0)) + r * NC;
    float best = -3.4e38f;
    int bi = 0;
    if (r < H) {
        #pragma unroll
        for (int q = 0; q < NC; ++q) {
            float v = row[q];
            if (v > best) { best = v; bi = q; }   // strict >: first max, matches jnp.argmax
        }
    }
    const int gidx = __shfl(bi, (lane & 31) + 32, 64);
    if (lane < H) {
        const int cell = chunk * H + r;
        const int t = TAB ? (cell / 6) : cell;
        const bool predP = (t < gtlen) && (bi < NC - 1);
        const bool gtP   = (gidx < NC - 1);
        const bool eq    = (bi == gidx);
        tp += (predP && gtP && eq) ? 1u : 0u;
        fp += (predP && !(gtP && eq)) ? 1u : 0u;
        fn += (gtP && !(predP && eq)) ? 1u : 0u;
    }
}

// Wave-private 2-deep pipeline; single LDS buffer is safe (same-wave DS ops are
// serviced in issue order — validated by R5/R6 passing). Next chunk's loads are
// issued before the current chunk's register use, so the compiler's implicit
// vmcnt wait is counted.
template<int NC, int H, bool TAB>
__device__ __forceinline__ void run_stream(const float* pred, const float* gt,
                                           int nchunks, int w, int nwaves,
                                           char* lbuf, int lane, int gtlen,
                                           unsigned& tp, unsigned& fp, unsigned& fn)
{
    constexpr int CB = H * NC * 4;
    const char* pb = (const char*)pred;
    const char* gb = (const char*)gt;

    int cur = w;
    if (cur >= nchunks) return;

    C6 A = load_chunk<CB>(pb + (size_t)cur * CB, gb + (size_t)cur * CB, lane);
    C6 B;

    while (true) {
        int nxt = cur + nwaves;
        if (nxt < nchunks)
            B = load_chunk<CB>(pb + (size_t)nxt * CB, gb + (size_t)nxt * CB, lane);
        __builtin_amdgcn_sched_barrier(0);   // pin next-chunk loads above A's use
        store_chunk<CB>(lbuf, lane, A);
        compute_chunk<NC, H, TAB>(lbuf, lane, cur, gtlen, tp, fp, fn);
        cur = nxt;
        if (cur >= nchunks) break;

        nxt = cur + nwaves;
        if (nxt < nchunks)
            A = load_chunk<CB>(pb + (size_t)nxt * CB, gb + (size_t)nxt * CB, lane);
        __builtin_amdgcn_sched_barrier(0);
        store_chunk<CB>(lbuf, lane, B);
        compute_chunk<NC, H, TAB>(lbuf, lane, cur, gtlen, tp, fp, fn);
        cur = nxt;
        if (cur >= nchunks) break;
    }
}

// ws layout (u32): [0]=tabTP [1]=tabFP [2]=tabFN [3]=f0TP [4]=f0FP [5]=f0FN
__global__ __launch_bounds__(256, 6) void count_kernel(
    const float* __restrict__ tab_pred, const float* __restrict__ tab_gt,
    const float* __restrict__ f0_pred,  const float* __restrict__ f0_gt,
    const int* __restrict__ gtlen_p, unsigned int* __restrict__ ws,
    int tabBlocks, int tabChunks, int f0Blocks, int f0Chunks)
{
    __shared__ __align__(16) char smem[4 * WAVE_LDS];   // 23040 B
    __shared__ unsigned red[3];

    const int tid  = threadIdx.x;
    const int lane = tid & 63;
    const int wid  = tid >> 6;
    if (tid < 3) red[tid] = 0;
    __syncthreads();

    const int gtlen = *gtlen_p;
    unsigned tp = 0, fp = 0, fn = 0;
    char* myLds = smem + wid * WAVE_LDS;

    int base;
    if ((int)blockIdx.x < tabBlocks) {
        base = 0;
        const int w = blockIdx.x * 4 + wid;
        run_stream<21, 32, true>(tab_pred, tab_gt, tabChunks, w, tabBlocks * 4,
                                 myLds, lane, gtlen, tp, fp, fn);
    } else {
        base = 3;
        const int w = (blockIdx.x - tabBlocks) * 4 + wid;
        run_stream<45, 16, false>(f0_pred, f0_gt, f0Chunks, w, f0Blocks * 4,
                                  myLds, lane, gtlen, tp, fp, fn);
    }

    atomicAdd(&red[0], tp);
    atomicAdd(&red[1], fp);
    atomicAdd(&red[2], fn);
    __syncthreads();
    if (tid == 0) {
        atomicAdd(&ws[base + 0], red[0]);
        atomicAdd(&ws[base + 1], red[1]);
        atomicAdd(&ws[base + 2], red[2]);
    }
}

__device__ __forceinline__ void write_scores(
    float TP, float TN, float FP, float FN, float* o)
{
    // matches jnp.nan_to_num(x/y): 0/0 -> 0
    float dp = TP + FP;
    float prec = (dp != 0.0f) ? TP / dp : 0.0f;
    float dr = TP + FN;
    float rec = (dr != 0.0f) ? TP / dr : 0.0f;
    float df = prec + rec;
    float f1 = (df != 0.0f) ? 2.0f * prec * rec / df : 0.0f;
    float acc = (TP + TN) / (TP + FN + TN + FP);
    o[0] = prec; o[1] = rec; o[2] = f1; o[3] = acc;
}

__global__ void score_kernel(const unsigned int* __restrict__ ws,
                             float* __restrict__ out,
                             unsigned long long tabTotal,
                             unsigned long long f0Total)
{
    if (blockIdx.x == 0 && threadIdx.x == 0) {
        unsigned long long ttp = ws[0], tfp = ws[1], tfn = ws[2];
        unsigned long long ftp = ws[3], ffp = ws[4], ffn = ws[5];
        unsigned long long ttn = tabTotal - ttp - tfp - tfn;
        unsigned long long ftn = f0Total - ftp - ffp - ffn;
        write_scores((float)ttp, (float)ttn, (float)tfp, (float)tfn, out);
        write_scores((float)ftp, (float)ftn, (float)ffp, (float)ffn, out + 4);
    }
}

extern "C" void kernel_launch(void* const* d_in, const int* in_sizes, int n_in,
                              void* d_out, int out_size, void* d_ws, size_t ws_size,
                              hipStream_t stream) {
    const float* tab_pred = (const float*)d_in[0];
    const float* F0_pred  = (const float*)d_in[1];
    const float* tab_gt   = (const float*)d_in[2];
    const float* F0_gt    = (const float*)d_in[3];
    const int*   gtlen    = (const int*)d_in[4];

    const int T = in_sizes[1] / 45;        // 500000
    const int ncells = T * 6;              // 3,000,000

    const int tabChunks = ncells / 32;     // 93750 (exact)
    const int f0Chunks  = T / 16;          // 31250 (exact)

    // 1536 blocks = 6 blocks/CU (LDS 23 KB/block x6 = 141 KB <= 160 KB).
    // Split by byte volume 504:180 -> 1132:404.
    const int tabBlocks = 1132;
    const int f0Blocks  = 404;

    unsigned int* ws = (unsigned int*)d_ws;
    hipMemsetAsync(d_ws, 0, 8 * sizeof(unsigned int), stream);

    count_kernel<<<tabBlocks + f0Blocks, 256, 0, stream>>>(
        tab_pred, tab_gt, F0_pred, F0_gt, gtlen, ws,
        tabBlocks, tabChunks, f0Blocks, f0Chunks);

    score_kernel<<<1, 1, 0, stream>>>(
        ws, (float*)d_out,
        (unsigned long long)ncells * 20,
        (unsigned long long)T * 44);
}

// Round 9
// 130.230 us; speedup vs baseline: 1.1227x; 1.1227x over previous
//
#include <hip/hip_runtime.h>

#define MAXCB    2880               // bytes per staged matrix chunk (max of 2688 tab / 2880 f0)
#define WAVE_LDS (2 * MAXCB)        // pred chunk + gt chunk per wave (5760 B)

// Native clang vector for nontemporal builtins (HIP_vector_type is rejected).
typedef float nfloat4 __attribute__((ext_vector_type(4)));

// Named members only — no arrays anywhere, so SROA keeps these in VGPRs.
struct C6 { nfloat4 p0, p1, p2, g0, g1, g2; };

__device__ __forceinline__ nfloat4 ntload(const char* a) {
    return __builtin_nontemporal_load((const nfloat4*)a);
}

// Chunk image: CB bytes per matrix, segments [0,1024), [1024,2048), [2048,CB).
// Third segment offset is CLAMPED (not branch-masked): lanes past the tail
// re-read / re-write the last 16B slot with identical data — branchless & uniform.
template<int CB>
__device__ __forceinline__ C6 load_chunk(const char* __restrict__ p,
                                         const char* __restrict__ g, int lane) {
    const int off = lane * 16;
    const int o2  = (off + 2048 <= CB - 16) ? (off + 2048) : (CB - 16);
    C6 c;
    c.p0 = ntload(p + off);
    c.p1 = ntload(p + 1024 + off);
    c.p2 = ntload(p + o2);
    c.g0 = ntload(g + off);
    c.g1 = ntload(g + 1024 + off);
    c.g2 = ntload(g + o2);
    return c;
}

template<int CB>
__device__ __forceinline__ void store_chunk(char* lbuf, int lane, const C6& c) {
    const int off = lane * 16;
    const int o2  = (off + 2048 <= CB - 16) ? (off + 2048) : (CB - 16);
    *(nfloat4*)(lbuf + off)                = c.p0;
    *(nfloat4*)(lbuf + 1024 + off)         = c.p1;
    *(nfloat4*)(lbuf + o2)                 = c.p2;
    *(nfloat4*)(lbuf + MAXCB + off)        = c.g0;
    *(nfloat4*)(lbuf + MAXCB + 1024 + off) = c.g1;
    *(nfloat4*)(lbuf + MAXCB + o2)         = c.g2;
}

// Lanes [0,H): argmax of pred rows; lanes [32,32+H): argmax of gt rows; shfl-combine.
template<int NC, int H, bool TAB>
__device__ __forceinline__ void compute_chunk(const char* lbuf, int lane, int chunk,
                                              int gtlen, unsigned& tp, unsigned& fp,
                                              unsigned& fn)
{
    const int r = lane & 31;
    const float* row = (const float*)(lbuf + ((lane >= 32) ? MAXCB : 0)) + r * NC;
    float best = -3.4e38f;
    int bi = 0;
    if (r < H) {
        #pragma unroll
        for (int q = 0; q < NC; ++q) {
            float v = row[q];
            if (v > best) { best = v; bi = q; }   // strict >: first max, matches jnp.argmax
        }
    }
    const int gidx = __shfl(bi, (lane & 31) + 32, 64);
    if (lane < H) {
        const int cell = chunk * H + r;
        const int t = TAB ? (cell / 6) : cell;
        const bool predP = (t < gtlen) && (bi < NC - 1);
        const bool gtP   = (gidx < NC - 1);
        const bool eq    = (bi == gidx);
        tp += (predP && gtP && eq) ? 1u : 0u;
        fp += (predP && !(gtP && eq)) ? 1u : 0u;
        fn += (gtP && !(predP && eq)) ? 1u : 0u;
    }
}

// Wave-private 2-deep pipeline; single LDS buffer is safe (same-wave DS ops are
// serviced in issue order — validated by R5/R6/R7 passing). Next chunk's loads
// are issued before the current chunk's register use, so the compiler's implicit
// vmcnt wait is counted.
template<int NC, int H, bool TAB>
__device__ __forceinline__ void run_stream(const float* pred, const float* gt,
                                           int nchunks, int w, int nwaves,
                                           char* lbuf, int lane, int gtlen,
                                           unsigned& tp, unsigned& fp, unsigned& fn)
{
    constexpr int CB = H * NC * 4;
    const char* pb = (const char*)pred;
    const char* gb = (const char*)gt;

    int cur = w;
    if (cur >= nchunks) return;

    C6 A = load_chunk<CB>(pb + (size_t)cur * CB, gb + (size_t)cur * CB, lane);
    C6 B;

    while (true) {
        int nxt = cur + nwaves;
        if (nxt < nchunks)
            B = load_chunk<CB>(pb + (size_t)nxt * CB, gb + (size_t)nxt * CB, lane);
        __builtin_amdgcn_sched_barrier(0);   // pin next-chunk loads above A's use
        store_chunk<CB>(lbuf, lane, A);
        compute_chunk<NC, H, TAB>(lbuf, lane, cur, gtlen, tp, fp, fn);
        cur = nxt;
        if (cur >= nchunks) break;

        nxt = cur + nwaves;
        if (nxt < nchunks)
            A = load_chunk<CB>(pb + (size_t)nxt * CB, gb + (size_t)nxt * CB, lane);
        __builtin_amdgcn_sched_barrier(0);
        store_chunk<CB>(lbuf, lane, B);
        compute_chunk<NC, H, TAB>(lbuf, lane, cur, gtlen, tp, fp, fn);
        cur = nxt;
        if (cur >= nchunks) break;
    }
}

// ws layout (u32): [0]=tabTP [1]=tabFP [2]=tabFN [3]=f0TP [4]=f0FP [5]=f0FN
__global__ __launch_bounds__(256, 4) void count_kernel(
    const float* __restrict__ tab_pred, const float* __restrict__ tab_gt,
    const float* __restrict__ f0_pred,  const float* __restrict__ f0_gt,
    const int* __restrict__ gtlen_p, unsigned int* __restrict__ ws,
    int tabBlocks, int tabChunks, int f0Blocks, int f0Chunks)
{
    __shared__ __align__(16) char smem[4 * WAVE_LDS];   // 23040 B
    __shared__ unsigned red[3];

    const int tid  = threadIdx.x;
    const int lane = tid & 63;
    const int wid  = tid >> 6;
    if (tid < 3) red[tid] = 0;
    __syncthreads();

    const int gtlen = *gtlen_p;
    unsigned tp = 0, fp = 0, fn = 0;
    char* myLds = smem + wid * WAVE_LDS;

    int base;
    if ((int)blockIdx.x < tabBlocks) {
        base = 0;
        const int w = blockIdx.x * 4 + wid;
        run_stream<21, 32, true>(tab_pred, tab_gt, tabChunks, w, tabBlocks * 4,
                                 myLds, lane, gtlen, tp, fp, fn);
    } else {
        base = 3;
        const int w = (blockIdx.x - tabBlocks) * 4 + wid;
        run_stream<45, 16, false>(f0_pred, f0_gt, f0Chunks, w, f0Blocks * 4,
                                  myLds, lane, gtlen, tp, fp, fn);
    }

    atomicAdd(&red[0], tp);
    atomicAdd(&red[1], fp);
    atomicAdd(&red[2], fn);
    __syncthreads();
    if (tid == 0) {
        atomicAdd(&ws[base + 0], red[0]);
        atomicAdd(&ws[base + 1], red[1]);
        atomicAdd(&ws[base + 2], red[2]);
    }
}

__device__ __forceinline__ void write_scores(
    float TP, float TN, float FP, float FN, float* o)
{
    // matches jnp.nan_to_num(x/y): 0/0 -> 0
    float dp = TP + FP;
    float prec = (dp != 0.0f) ? TP / dp : 0.0f;
    float dr = TP + FN;
    float rec = (dr != 0.0f) ? TP / dr : 0.0f;
    float df = prec + rec;
    float f1 = (df != 0.0f) ? 2.0f * prec * rec / df : 0.0f;
    float acc = (TP + TN) / (TP + FN + TN + FP);
    o[0] = prec; o[1] = rec; o[2] = f1; o[3] = acc;
}

__global__ void score_kernel(const unsigned int* __restrict__ ws,
                             float* __restrict__ out,
                             unsigned long long tabTotal,
                             unsigned long long f0Total)
{
    if (blockIdx.x == 0 && threadIdx.x == 0) {
        unsigned long long ttp = ws[0], tfp = ws[1], tfn = ws[2];
        unsigned long long ftp = ws[3], ffp = ws[4], ffn = ws[5];
        unsigned long long ttn = tabTotal - ttp - tfp - tfn;
        unsigned long long ftn = f0Total - ftp - ffp - ffn;
        write_scores((float)ttp, (float)ttn, (float)tfp, (float)tfn, out);
        write_scores((float)ftp, (float)ftn, (float)ffp, (float)ffn, out + 4);
    }
}

extern "C" void kernel_launch(void* const* d_in, const int* in_sizes, int n_in,
                              void* d_out, int out_size, void* d_ws, size_t ws_size,
                              hipStream_t stream) {
    const float* tab_pred = (const float*)d_in[0];
    const float* F0_pred  = (const float*)d_in[1];
    const float* tab_gt   = (const float*)d_in[2];
    const float* F0_gt    = (const float*)d_in[3];
    const int*   gtlen    = (const int*)d_in[4];

    const int T = in_sizes[1] / 45;        // 500000
    const int ncells = T * 6;              // 3,000,000

    const int tabChunks = ncells / 32;     // 93750 (exact)
    const int f0Chunks  = T / 16;          // 31250 (exact)

    // 1024 blocks = 4 blocks/CU (R6's best config). Split by byte volume 504:180.
    const int tabBlocks = 754;
    const int f0Blocks  = 270;

    unsigned int* ws = (unsigned int*)d_ws;
    (void)hipMemsetAsync(d_ws, 0, 8 * sizeof(unsigned int), stream);

    count_kernel<<<tabBlocks + f0Blocks, 256, 0, stream>>>(
        tab_pred, tab_gt, F0_pred, F0_gt, gtlen, ws,
        tabBlocks, tabChunks, f0Blocks, f0Chunks);

    score_kernel<<<1, 1, 0, stream>>>(
        ws, (float*)d_out,
        (unsigned long long)ncells * 20,
        (unsigned long long)T * 44);
}

// Round 10
// 127.627 us; speedup vs baseline: 1.1456x; 1.0204x over previous
//
#include <hip/hip_runtime.h>

#define MAXCB    2880               // bytes per staged matrix chunk (max of 2688 tab / 2880 f0)
#define WAVE_LDS (2 * MAXCB)        // pred chunk + gt chunk per wave (5760 B)
#define TABBLOCKS 754
#define F0BLOCKS  270
#define NBLOCKS   (TABBLOCKS + F0BLOCKS)

// Native clang vector for nontemporal builtins (HIP_vector_type is rejected).
typedef float nfloat4 __attribute__((ext_vector_type(4)));

// Named members only — no arrays anywhere, so SROA keeps these in VGPRs.
struct C6 { nfloat4 p0, p1, p2, g0, g1, g2; };

__device__ __forceinline__ nfloat4 ntload(const char* a) {
    return __builtin_nontemporal_load((const nfloat4*)a);
}

// Chunk image: CB bytes per matrix, segments [0,1024), [1024,2048), [2048,CB).
// Third segment offset is CLAMPED (not branch-masked): lanes past the tail
// re-read / re-write the last 16B slot with identical data — branchless & uniform.
template<int CB>
__device__ __forceinline__ C6 load_chunk(const char* __restrict__ p,
                                         const char* __restrict__ g, int lane) {
    const int off = lane * 16;
    const int o2  = (off + 2048 <= CB - 16) ? (off + 2048) : (CB - 16);
    C6 c;
    c.p0 = ntload(p + off);
    c.p1 = ntload(p + 1024 + off);
    c.p2 = ntload(p + o2);
    c.g0 = ntload(g + off);
    c.g1 = ntload(g + 1024 + off);
    c.g2 = ntload(g + o2);
    return c;
}

template<int CB>
__device__ __forceinline__ void store_chunk(char* lbuf, int lane, const C6& c) {
    const int off = lane * 16;
    const int o2  = (off + 2048 <= CB - 16) ? (off + 2048) : (CB - 16);
    *(nfloat4*)(lbuf + off)                = c.p0;
    *(nfloat4*)(lbuf + 1024 + off)         = c.p1;
    *(nfloat4*)(lbuf + o2)                 = c.p2;
    *(nfloat4*)(lbuf + MAXCB + off)        = c.g0;
    *(nfloat4*)(lbuf + MAXCB + 1024 + off) = c.g1;
    *(nfloat4*)(lbuf + MAXCB + o2)         = c.g2;
}

// Lanes [0,H): argmax of pred rows; lanes [32,32+H): argmax of gt rows; shfl-combine.
template<int NC, int H, bool TAB>
__device__ __forceinline__ void compute_chunk(const char* lbuf, int lane, int chunk,
                                              int gtlen, unsigned& tp, unsigned& fp,
                                              unsigned& fn)
{
    const int r = lane & 31;
    const float* row = (const float*)(lbuf + ((lane >= 32) ? MAXCB : 0)) + r * NC;
    float best = -3.4e38f;
    int bi = 0;
    if (r < H) {
        #pragma unroll
        for (int q = 0; q < NC; ++q) {
            float v = row[q];
            if (v > best) { best = v; bi = q; }   // strict >: first max, matches jnp.argmax
        }
    }
    const int gidx = __shfl(bi, (lane & 31) + 32, 64);
    if (lane < H) {
        const int cell = chunk * H + r;
        const int t = TAB ? (cell / 6) : cell;
        const bool predP = (t < gtlen) && (bi < NC - 1);
        const bool gtP   = (gidx < NC - 1);
        const bool eq    = (bi == gidx);
        tp += (predP && gtP && eq) ? 1u : 0u;
        fp += (predP && !(gtP && eq)) ? 1u : 0u;
        fn += (gtP && !(predP && eq)) ? 1u : 0u;
    }
}

// Wave-private 2-deep pipeline; single LDS buffer is safe (same-wave DS ops are
// serviced in issue order — validated R5-R9). Next chunk's loads are issued
// before the current chunk's register use → counted implicit vmcnt wait.
template<int NC, int H, bool TAB>
__device__ __forceinline__ void run_stream(const float* pred, const float* gt,
                                           int nchunks, int w, int nwaves,
                                           char* lbuf, int lane, int gtlen,
                                           unsigned& tp, unsigned& fp, unsigned& fn)
{
    constexpr int CB = H * NC * 4;
    const char* pb = (const char*)pred;
    const char* gb = (const char*)gt;

    int cur = w;
    if (cur >= nchunks) return;

    C6 A = load_chunk<CB>(pb + (size_t)cur * CB, gb + (size_t)cur * CB, lane);
    C6 B;

    while (true) {
        int nxt = cur + nwaves;
        if (nxt < nchunks)
            B = load_chunk<CB>(pb + (size_t)nxt * CB, gb + (size_t)nxt * CB, lane);
        __builtin_amdgcn_sched_barrier(0);   // pin next-chunk loads above A's use
        store_chunk<CB>(lbuf, lane, A);
        compute_chunk<NC, H, TAB>(lbuf, lane, cur, gtlen, tp, fp, fn);
        cur = nxt;
        if (cur >= nchunks) break;

        nxt = cur + nwaves;
        if (nxt < nchunks)
            A = load_chunk<CB>(pb + (size_t)nxt * CB, gb + (size_t)nxt * CB, lane);
        __builtin_amdgcn_sched_barrier(0);
        store_chunk<CB>(lbuf, lane, B);
        compute_chunk<NC, H, TAB>(lbuf, lane, cur, gtlen, tp, fp, fn);
        cur = nxt;
        if (cur >= nchunks) break;
    }
}

// ws layout (u32): slots[bid*4 + {0,1,2}] = block's {TP,FP,FN} partials.
// Every slot is written unconditionally every call -> no init needed, no
// cross-call state, no atomics.
__global__ __launch_bounds__(256, 4) void count_kernel(
    const float* __restrict__ tab_pred, const float* __restrict__ tab_gt,
    const float* __restrict__ f0_pred,  const float* __restrict__ f0_gt,
    const int* __restrict__ gtlen_p, unsigned int* __restrict__ slots,
    int tabChunks, int f0Chunks)
{
    __shared__ __align__(16) char smem[4 * WAVE_LDS];   // 23040 B
    __shared__ unsigned red[3];

    const int tid  = threadIdx.x;
    const int lane = tid & 63;
    const int wid  = tid >> 6;
    if (tid < 3) red[tid] = 0;
    __syncthreads();

    const int gtlen = *gtlen_p;
    unsigned tp = 0, fp = 0, fn = 0;
    char* myLds = smem + wid * WAVE_LDS;

    if ((int)blockIdx.x < TABBLOCKS) {
        const int w = blockIdx.x * 4 + wid;
        run_stream<21, 32, true>(tab_pred, tab_gt, tabChunks, w, TABBLOCKS * 4,
                                 myLds, lane, gtlen, tp, fp, fn);
    } else {
        const int w = (blockIdx.x - TABBLOCKS) * 4 + wid;
        run_stream<45, 16, false>(f0_pred, f0_gt, f0Chunks, w, F0BLOCKS * 4,
                                  myLds, lane, gtlen, tp, fp, fn);
    }

    atomicAdd(&red[0], tp);
    atomicAdd(&red[1], fp);
    atomicAdd(&red[2], fn);
    __syncthreads();
    if (tid < 3) slots[blockIdx.x * 4 + tid] = red[tid];
}

__device__ __forceinline__ void write_scores(
    float TP, float TN, float FP, float FN, float* o)
{
    // matches jnp.nan_to_num(x/y): 0/0 -> 0
    float dp = TP + FP;
    float prec = (dp != 0.0f) ? TP / dp : 0.0f;
    float dr = TP + FN;
    float rec = (dr != 0.0f) ? TP / dr : 0.0f;
    float df = prec + rec;
    float f1 = (df != 0.0f) ? 2.0f * prec * rec / df : 0.0f;
    float acc = (TP + TN) / (TP + FN + TN + FP);
    o[0] = prec; o[1] = rec; o[2] = f1; o[3] = acc;
}

__global__ __launch_bounds__(256) void score_kernel(
    const unsigned int* __restrict__ slots, float* __restrict__ out,
    unsigned long long tabTotal, unsigned long long f0Total)
{
    __shared__ unsigned acc[6];
    const int tid = threadIdx.x;
    if (tid < 6) acc[tid] = 0;
    __syncthreads();

    unsigned t0 = 0, t1 = 0, t2 = 0, f0 = 0, f1 = 0, f2 = 0;
    for (int b = tid; b < NBLOCKS; b += 256) {
        unsigned a = slots[b * 4 + 0], c = slots[b * 4 + 1], d = slots[b * 4 + 2];
        if (b < TABBLOCKS) { t0 += a; t1 += c; t2 += d; }
        else               { f0 += a; f1 += c; f2 += d; }
    }
    atomicAdd(&acc[0], t0); atomicAdd(&acc[1], t1); atomicAdd(&acc[2], t2);
    atomicAdd(&acc[3], f0); atomicAdd(&acc[4], f1); atomicAdd(&acc[5], f2);
    __syncthreads();

    if (tid == 0) {
        unsigned long long ttp = acc[0], tfp = acc[1], tfn = acc[2];
        unsigned long long ftp = acc[3], ffp = acc[4], ffn = acc[5];
        unsigned long long ttn = tabTotal - ttp - tfp - tfn;
        unsigned long long ftn = f0Total - ftp - ffp - ffn;
        write_scores((float)ttp, (float)ttn, (float)tfp, (float)tfn, out);
        write_scores((float)ftp, (float)ftn, (float)ffp, (float)ffn, out + 4);
    }
}

extern "C" void kernel_launch(void* const* d_in, const int* in_sizes, int n_in,
                              void* d_out, int out_size, void* d_ws, size_t ws_size,
                              hipStream_t stream) {
    const float* tab_pred = (const float*)d_in[0];
    const float* F0_pred  = (const float*)d_in[1];
    const float* tab_gt   = (const float*)d_in[2];
    const float* F0_gt    = (const float*)d_in[3];
    const int*   gtlen    = (const int*)d_in[4];

    const int T = in_sizes[1] / 45;        // 500000
    const int ncells = T * 6;              // 3,000,000

    const int tabChunks = ncells / 32;     // 93750 (exact)
    const int f0Chunks  = T / 16;          // 31250 (exact)

    unsigned int* slots = (unsigned int*)d_ws;   // NBLOCKS*4 u32 = 16 KB

    count_kernel<<<NBLOCKS, 256, 0, stream>>>(
        tab_pred, tab_gt, F0_pred, F0_gt, gtlen, slots, tabChunks, f0Chunks);

    score_kernel<<<1, 256, 0, stream>>>(
        slots, (float*)d_out,
        (unsigned long long)ncells * 20,
        (unsigned long long)T * 44);
}